// Round 1
// baseline (365.320 us; speedup 1.0000x reference)
//
#include <hip/hip_runtime.h>

#define DEV __device__ __forceinline__

typedef __attribute__((ext_vector_type(8))) short bf16x8;
typedef __attribute__((ext_vector_type(4))) float f32x4;

static constexpr int Bn = 8;
static constexpr int Sn = 2048;
static constexpr int Dn = 1024;
static constexpr int Mtot = Bn * Sn;   // 16384

DEV void gload_lds16(const void* g, void* l) {
  __builtin_amdgcn_global_load_lds(
      (const __attribute__((address_space(1))) void*)g,
      (__attribute__((address_space(3))) void*)l, 16, 0, 0);
}

DEV float bf2f(unsigned short u) {
  union { unsigned int i; float f; } c;
  c.i = ((unsigned int)u) << 16;
  return c.f;
}
DEV unsigned short f2bf(float f) {
  union { float f; unsigned int i; } c;
  c.f = f;
  unsigned int lsb = (c.i >> 16) & 1u;
  return (unsigned short)((c.i + 0x7fffu + lsb) >> 16);
}

// ---------------------------------------------------------------- prep:
// masks[b][s] = sin(|sum_d x|), xbf = bf16(x). One wave per row.
__global__ __launch_bounds__(256) void prep_kernel(const float* __restrict__ x,
                                                   unsigned short* __restrict__ xbf,
                                                   float* __restrict__ masks) {
  const int w = threadIdx.x >> 6, l = threadIdx.x & 63;
  const int row = blockIdx.x * 4 + w;
  const float* xr = x + (size_t)row * Dn;
  float s = 0.f;
  unsigned int ow[8];
  #pragma unroll
  for (int i = 0; i < 4; i++) {
    float4 v = ((const float4*)xr)[l * 4 + i];
    s += (v.x + v.y) + (v.z + v.w);
    ow[i * 2 + 0] = (unsigned int)f2bf(v.x) | ((unsigned int)f2bf(v.y) << 16);
    ow[i * 2 + 1] = (unsigned int)f2bf(v.z) | ((unsigned int)f2bf(v.w) << 16);
  }
  uint4* dst = (uint4*)(xbf + (size_t)row * Dn + l * 16);
  dst[0] = make_uint4(ow[0], ow[1], ow[2], ow[3]);
  dst[1] = make_uint4(ow[4], ow[5], ow[6], ow[7]);
  #pragma unroll
  for (int off = 32; off > 0; off >>= 1) s += __shfl_xor(s, off);
  if (l == 0) masks[row] = sinf(fabsf(s));
}

// ---------------------------------------------------------------- Wt:
// Wt[which][f][d] = bf16(W[d][f])  (transpose so QKV GEMM is NT)
__global__ __launch_bounds__(256) void wt_kernel(const float* __restrict__ Wq,
                                                 const float* __restrict__ Wk,
                                                 const float* __restrict__ Wv,
                                                 unsigned short* __restrict__ Wt) {
  const float* W = blockIdx.z == 0 ? Wq : (blockIdx.z == 1 ? Wk : Wv);
  unsigned short* out = Wt + (size_t)blockIdx.z * Dn * Dn;
  __shared__ float tile[32][33];
  const int r0 = blockIdx.y * 32, c0 = blockIdx.x * 32;
  const int t = threadIdx.x;
  {
    const int r = t >> 3, c4 = (t & 7) * 4;
    float4 v = *(const float4*)&W[(size_t)(r0 + r) * Dn + c0 + c4];
    tile[r][c4 + 0] = v.x; tile[r][c4 + 1] = v.y;
    tile[r][c4 + 2] = v.z; tile[r][c4 + 3] = v.w;
  }
  __syncthreads();
  {
    const int f = t >> 3, d4 = (t & 7) * 4;
    unsigned short o[4];
    #pragma unroll
    for (int i = 0; i < 4; i++) o[i] = f2bf(tile[d4 + i][f]);
    unsigned int p0 = (unsigned int)o[0] | ((unsigned int)o[1] << 16);
    unsigned int p1 = (unsigned int)o[2] | ((unsigned int)o[3] << 16);
    *(uint2*)&out[(size_t)(c0 + f) * Dn + r0 + d4] = make_uint2(p0, p1);
  }
}

// ---------------------------------------------------------------- GEMM core:
// NT bf16 GEMM, 128x128 tile, BK=64, 4 waves each 64x64, global_load_lds w16,
// XOR-swizzled staging (pre-swizzled global source, swizzled LDS read).
DEV void gemm_core(const unsigned short* __restrict__ Ag, int lda,
                   const unsigned short* __restrict__ Bg, int ldb,
                   int K, unsigned short* ldsA, unsigned short* ldsB,
                   f32x4 acc[4][4]) {
  const int tid = threadIdx.x;
  const int l = tid & 63;
  const int w = tid >> 6;
  const int wr = w >> 1, wc = w & 1;
  const int lr = l & 15, lk = l >> 4;
  #pragma unroll
  for (int mi = 0; mi < 4; mi++)
    #pragma unroll
    for (int ni = 0; ni < 4; ni++)
      #pragma unroll
      for (int q = 0; q < 4; q++) acc[mi][ni][q] = 0.f;

  for (int kt = 0; kt < K; kt += 64) {
    #pragma unroll
    for (int i = 0; i < 4; i++) {
      const int idx = i * 256 + tid;
      const int row = idx >> 3, cch = idx & 7;
      const int sc = cch ^ (row & 7);   // pre-swizzle the SOURCE (linear LDS dest)
      gload_lds16(Ag + (size_t)row * lda + kt + sc * 8, ldsA + idx * 8);
      gload_lds16(Bg + (size_t)row * ldb + kt + sc * 8, ldsB + idx * 8);
    }
    __syncthreads();
    #pragma unroll
    for (int kk = 0; kk < 2; kk++) {
      bf16x8 af[4], bfv[4];
      #pragma unroll
      for (int mi = 0; mi < 4; mi++) {
        const int row = wr * 64 + mi * 16 + lr;
        const int ch = (kk * 4 + lk) ^ (row & 7);  // swizzled read
        af[mi] = *(const bf16x8*)(ldsA + row * 64 + ch * 8);
      }
      #pragma unroll
      for (int ni = 0; ni < 4; ni++) {
        const int row = wc * 64 + ni * 16 + lr;
        const int ch = (kk * 4 + lk) ^ (row & 7);
        bfv[ni] = *(const bf16x8*)(ldsB + row * 64 + ch * 8);
      }
      #pragma unroll
      for (int mi = 0; mi < 4; mi++)
        #pragma unroll
        for (int ni = 0; ni < 4; ni++)
          acc[mi][ni] = __builtin_amdgcn_mfma_f32_16x16x32_bf16(af[mi], bfv[ni], acc[mi][ni], 0, 0, 0);
    }
    __syncthreads();
  }
}

// ---------------------------------------------------------------- QKV:
// q/k row-major bf16; v written transposed vT[b][d][s] via LDS transpose.
__global__ __launch_bounds__(256) void qkv_kernel(
    const unsigned short* __restrict__ xbf, const unsigned short* __restrict__ Wt,
    const float* __restrict__ bq, const float* __restrict__ bk,
    const float* __restrict__ bv,
    unsigned short* __restrict__ qo, unsigned short* __restrict__ ko,
    unsigned short* __restrict__ vT) {
  __shared__ unsigned short lds[16384];  // 32KB: A|B staging, reused for transpose
  const int which = blockIdx.z;
  const int m0 = blockIdx.y * 128, n0 = blockIdx.x * 128;
  const unsigned short* Ag = xbf + (size_t)m0 * Dn;
  const unsigned short* Bg = Wt + (size_t)which * Dn * Dn + (size_t)n0 * Dn;
  f32x4 acc[4][4];
  gemm_core(Ag, Dn, Bg, Dn, Dn, lds, lds + 8192, acc);

  const float* bias = which == 0 ? bq : (which == 1 ? bk : bv);
  const int tid = threadIdx.x;
  const int l = tid & 63, w = tid >> 6;
  const int wr = w >> 1, wc = w & 1;
  const int lr = l & 15, lk = l >> 4;

  if (which < 2) {
    unsigned short* out = which == 0 ? qo : ko;
    #pragma unroll
    for (int mi = 0; mi < 4; mi++) {
      #pragma unroll
      for (int ni = 0; ni < 4; ni++) {
        const int col = n0 + wc * 64 + ni * 16 + lr;
        const float bcol = bias[col];
        #pragma unroll
        for (int j = 0; j < 4; j++) {
          const int row = m0 + wr * 64 + mi * 16 + lk * 4 + j;
          out[(size_t)row * Dn + col] = f2bf(fmaxf(acc[mi][ni][j] + bcol, 0.f));
        }
      }
    }
  } else {
    // stage transposed tile into LDS (trans[c][r], bank-swizzled), then
    // coalesced writes of vT rows (d-major).
    #pragma unroll
    for (int mi = 0; mi < 4; mi++) {
      const int r0 = wr * 64 + mi * 16 + lk * 4;
      const int rc = r0 >> 2;  // 8B chunk of 4 rows
      #pragma unroll
      for (int ni = 0; ni < 4; ni++) {
        const int c = wc * 64 + ni * 16 + lr;
        const float bcol = bias[n0 + c];
        unsigned short o0 = f2bf(fmaxf(acc[mi][ni][0] + bcol, 0.f));
        unsigned short o1 = f2bf(fmaxf(acc[mi][ni][1] + bcol, 0.f));
        unsigned short o2 = f2bf(fmaxf(acc[mi][ni][2] + bcol, 0.f));
        unsigned short o3 = f2bf(fmaxf(acc[mi][ni][3] + bcol, 0.f));
        const int rcs = rc ^ (c & 31);
        *(uint2*)&lds[c * 128 + rcs * 4] =
            make_uint2((unsigned int)o0 | ((unsigned int)o1 << 16),
                       (unsigned int)o2 | ((unsigned int)o3 << 16));
      }
    }
    __syncthreads();
    const int b = m0 >> 11;
    const int s0 = m0 & (Sn - 1);
    #pragma unroll
    for (int it = 0; it < 16; it++) {
      const int lin = it * 256 + tid;
      const int c = lin >> 5;    // d-local 0..127
      const int rc = lin & 31;   // s-chunk
      const int rcs = rc ^ (c & 31);
      uint2 v = *(const uint2*)&lds[c * 128 + rcs * 4];
      *(uint2*)&vT[(size_t)b * Dn * Sn + (size_t)(n0 + c) * Sn + s0 + rc * 4] = v;
    }
  }
}

// ---------------------------------------------------------------- scores:
// P[b][q][k] = mask_k==0 ? 0 : exp(q·k/32)   (unnormalized, bf16)
// lpart[b][q][nt] = partial row sums (deterministic, no atomics)
__global__ __launch_bounds__(256) void scores_kernel(
    const unsigned short* __restrict__ qbf, const unsigned short* __restrict__ kbf,
    const float* __restrict__ masks, unsigned short* __restrict__ P,
    float* __restrict__ lpart) {
  __shared__ unsigned short lds[16384];
  __shared__ float psum[2][128];
  const int b = blockIdx.z;
  const int m0 = blockIdx.y * 128, n0 = blockIdx.x * 128;
  const unsigned short* Ag = qbf + ((size_t)b * Sn + m0) * Dn;
  const unsigned short* Bg = kbf + ((size_t)b * Sn + n0) * Dn;
  f32x4 acc[4][4];
  gemm_core(Ag, Dn, Bg, Dn, Dn, lds, lds + 8192, acc);

  const int tid = threadIdx.x;
  const int l = tid & 63, w = tid >> 6;
  const int wr = w >> 1, wc = w & 1;
  const int lr = l & 15, lk = l >> 4;

  float rs[4][4];
  #pragma unroll
  for (int mi = 0; mi < 4; mi++)
    #pragma unroll
    for (int j = 0; j < 4; j++) rs[mi][j] = 0.f;

  unsigned short* Pb = P + (size_t)b * Sn * Sn;
  #pragma unroll
  for (int ni = 0; ni < 4; ni++) {
    const int col = n0 + wc * 64 + ni * 16 + lr;
    const float mk = masks[b * Sn + col];
    const bool dead = (mk == 0.f);
    #pragma unroll
    for (int mi = 0; mi < 4; mi++) {
      #pragma unroll
      for (int j = 0; j < 4; j++) {
        const float s = acc[mi][ni][j] * 0.03125f;  // 1/sqrt(1024)
        const float p = dead ? 0.f : __expf(s);     // s>=0 (ReLU'd q,k): no overflow risk
        const unsigned short pq = f2bf(p);
        const int row = m0 + wr * 64 + mi * 16 + lk * 4 + j;
        Pb[(size_t)row * Sn + col] = pq;
        rs[mi][j] += bf2f(pq);  // sum what PV will actually read
      }
    }
  }
  #pragma unroll
  for (int mi = 0; mi < 4; mi++)
    #pragma unroll
    for (int j = 0; j < 4; j++) {
      float v = rs[mi][j];
      v += __shfl_xor(v, 1); v += __shfl_xor(v, 2);
      v += __shfl_xor(v, 4); v += __shfl_xor(v, 8);
      rs[mi][j] = v;
    }
  if (lr == 0) {
    #pragma unroll
    for (int mi = 0; mi < 4; mi++)
      #pragma unroll
      for (int j = 0; j < 4; j++)
        psum[wc][wr * 64 + mi * 16 + lk * 4 + j] = rs[mi][j];
  }
  __syncthreads();
  if (tid < 128) {
    const float v = psum[0][tid] + psum[1][tid];
    lpart[((size_t)b * Sn + m0 + tid) * 16 + blockIdx.x] = v;
  }
}

// ---------------------------------------------------------------- reduce:
// scale[b][q] = mask_q / sum_k P
__global__ __launch_bounds__(256) void reduce_kernel(const float* __restrict__ lpart,
                                                     const float* __restrict__ masks,
                                                     float* __restrict__ scale) {
  const int r = blockIdx.x * 256 + threadIdx.x;
  const float4* p = (const float4*)(lpart + (size_t)r * 16);
  float4 a = p[0], b = p[1], c = p[2], d = p[3];
  const float sum = ((a.x + a.y) + (a.z + a.w)) + ((b.x + b.y) + (b.z + b.w)) +
                    ((c.x + c.y) + (c.z + c.w)) + ((d.x + d.y) + (d.z + d.w));
  scale[r] = masks[r] / sum;
}

// ---------------------------------------------------------------- PV:
// out[b][q][d] = (P[b] @ vT[b]^T)*scale + q_residual
__global__ __launch_bounds__(256) void pv_kernel(
    const unsigned short* __restrict__ P, const unsigned short* __restrict__ vT,
    const float* __restrict__ scale, const unsigned short* __restrict__ qbf,
    float* __restrict__ out) {
  __shared__ unsigned short lds[16384];
  const int b = blockIdx.z;
  const int m0 = blockIdx.y * 128, n0 = blockIdx.x * 128;
  const unsigned short* Ag = P + (size_t)b * Sn * Sn + (size_t)m0 * Sn;
  const unsigned short* Bg = vT + (size_t)b * Dn * Sn + (size_t)n0 * Sn;
  f32x4 acc[4][4];
  gemm_core(Ag, Sn, Bg, Sn, Sn, lds, lds + 8192, acc);

  const int tid = threadIdx.x;
  const int l = tid & 63, w = tid >> 6;
  const int wr = w >> 1, wc = w & 1;
  const int lr = l & 15, lk = l >> 4;
  #pragma unroll
  for (int mi = 0; mi < 4; mi++) {
    #pragma unroll
    for (int j = 0; j < 4; j++) {
      const int row = m0 + wr * 64 + mi * 16 + lk * 4 + j;
      const float sc = scale[b * Sn + row];
      const size_t rbase = ((size_t)b * Sn + row) * Dn;
      #pragma unroll
      for (int ni = 0; ni < 4; ni++) {
        const int col = n0 + wc * 64 + ni * 16 + lr;
        out[rbase + col] = acc[mi][ni][j] * sc + bf2f(qbf[rbase + col]);
      }
    }
  }
}

// ---------------------------------------------------------------- launch
extern "C" void kernel_launch(void* const* d_in, const int* in_sizes, int n_in,
                              void* d_out, int out_size, void* d_ws, size_t ws_size,
                              hipStream_t stream) {
  const float* x  = (const float*)d_in[0];
  const float* Wq = (const float*)d_in[1];
  const float* bq = (const float*)d_in[2];
  const float* Wk = (const float*)d_in[3];
  const float* bk = (const float*)d_in[4];
  const float* Wv = (const float*)d_in[5];
  const float* bv = (const float*)d_in[6];
  float* out = (float*)d_out;

  char* ws = (char*)d_ws;
  size_t off = 0;
  auto alloc = [&](size_t bytes) {
    char* p = ws + off;
    off += (bytes + 255) & ~(size_t)255;
    return p;
  };
  unsigned short* xbf = (unsigned short*)alloc((size_t)Mtot * Dn * 2);
  unsigned short* qbf = (unsigned short*)alloc((size_t)Mtot * Dn * 2);
  unsigned short* kbf = (unsigned short*)alloc((size_t)Mtot * Dn * 2);
  unsigned short* vT  = (unsigned short*)alloc((size_t)Bn * Dn * Sn * 2);
  unsigned short* P   = (unsigned short*)alloc((size_t)Bn * Sn * Sn * 2);
  unsigned short* Wt  = (unsigned short*)alloc((size_t)3 * Dn * Dn * 2);
  float* masks = (float*)alloc((size_t)Mtot * 4);
  float* lpart = (float*)alloc((size_t)Mtot * 16 * 4);
  float* scale = (float*)alloc((size_t)Mtot * 4);

  prep_kernel<<<Mtot / 4, 256, 0, stream>>>(x, xbf, masks);
  wt_kernel<<<dim3(32, 32, 3), 256, 0, stream>>>(Wq, Wk, Wv, Wt);
  qkv_kernel<<<dim3(Dn / 128, Mtot / 128, 3), 256, 0, stream>>>(xbf, Wt, bq, bk, bv,
                                                                qbf, kbf, vT);
  scores_kernel<<<dim3(Sn / 128, Sn / 128, Bn), 256, 0, stream>>>(qbf, kbf, masks, P, lpart);
  reduce_kernel<<<Mtot / 256, 256, 0, stream>>>(lpart, masks, scale);
  pv_kernel<<<dim3(Dn / 128, Sn / 128, Bn), 256, 0, stream>>>(P, vT, scale, qbf, out);
}

// Round 2
// 359.566 us; speedup vs baseline: 1.0160x; 1.0160x over previous
//
#include <hip/hip_runtime.h>

#define DEV __device__ __forceinline__

typedef __attribute__((ext_vector_type(8))) short bf16x8;
typedef __attribute__((ext_vector_type(4))) float f32x4;

static constexpr int Bn = 8;
static constexpr int Sn = 2048;
static constexpr int Dn = 1024;
static constexpr int Mtot = Bn * Sn;   // 16384

// per-operand LDS buffer: 256 rows x 32 k bf16 = 8192 shorts (16KB)
// one tile buffer = A + B = 16384 shorts (32KB); 3 buffers = 96KB
static constexpr int BUF_HALF = 8192;
static constexpr int BUF_SZ = 16384;

DEV void gload_lds16(const void* g, void* l) {
  __builtin_amdgcn_global_load_lds(
      (const __attribute__((address_space(1))) void*)g,
      (__attribute__((address_space(3))) void*)l, 16, 0, 0);
}

DEV float bf2f(unsigned short u) {
  union { unsigned int i; float f; } c;
  c.i = ((unsigned int)u) << 16;
  return c.f;
}
DEV unsigned short f2bf(float f) {
  union { float f; unsigned int i; } c;
  c.f = f;
  unsigned int lsb = (c.i >> 16) & 1u;
  return (unsigned short)((c.i + 0x7fffu + lsb) >> 16);
}

// ---------------------------------------------------------------- prep:
// masks[b][s] = sin(|sum_d x|), xbf = bf16(x). One wave per row, coalesced.
__global__ __launch_bounds__(256) void prep_kernel(const float* __restrict__ x,
                                                   unsigned short* __restrict__ xbf,
                                                   float* __restrict__ masks) {
  const int w = threadIdx.x >> 6, l = threadIdx.x & 63;
  const int row = blockIdx.x * 4 + w;
  const float* xr = x + (size_t)row * Dn;
  unsigned short* xo = xbf + (size_t)row * Dn;
  float s = 0.f;
  #pragma unroll
  for (int i = 0; i < 4; i++) {
    float4 v = ((const float4*)xr)[i * 64 + l];
    s += (v.x + v.y) + (v.z + v.w);
    unsigned int p0 = (unsigned int)f2bf(v.x) | ((unsigned int)f2bf(v.y) << 16);
    unsigned int p1 = (unsigned int)f2bf(v.z) | ((unsigned int)f2bf(v.w) << 16);
    *(uint2*)&xo[i * 256 + l * 4] = make_uint2(p0, p1);
  }
  #pragma unroll
  for (int off = 32; off > 0; off >>= 1) s += __shfl_xor(s, off);
  if (l == 0) masks[row] = sinf(fabsf(s));
}

// ---------------------------------------------------------------- Wt:
// Wt[which][f][d] = bf16(W[d][f])  (transpose so QKV GEMM is NT)
__global__ __launch_bounds__(256) void wt_kernel(const float* __restrict__ Wq,
                                                 const float* __restrict__ Wk,
                                                 const float* __restrict__ Wv,
                                                 unsigned short* __restrict__ Wt) {
  const float* W = blockIdx.z == 0 ? Wq : (blockIdx.z == 1 ? Wk : Wv);
  unsigned short* out = Wt + (size_t)blockIdx.z * Dn * Dn;
  __shared__ float tile[32][33];
  const int r0 = blockIdx.y * 32, c0 = blockIdx.x * 32;
  const int t = threadIdx.x;
  {
    const int r = t >> 3, c4 = (t & 7) * 4;
    float4 v = *(const float4*)&W[(size_t)(r0 + r) * Dn + c0 + c4];
    tile[r][c4 + 0] = v.x; tile[r][c4 + 1] = v.y;
    tile[r][c4 + 2] = v.z; tile[r][c4 + 3] = v.w;
  }
  __syncthreads();
  {
    const int f = t >> 3, d4 = (t & 7) * 4;
    unsigned short o[4];
    #pragma unroll
    for (int i = 0; i < 4; i++) o[i] = f2bf(tile[d4 + i][f]);
    unsigned int p0 = (unsigned int)o[0] | ((unsigned int)o[1] << 16);
    unsigned int p1 = (unsigned int)o[2] | ((unsigned int)o[3] << 16);
    *(uint2*)&out[(size_t)(c0 + f) * Dn + r0 + d4] = make_uint2(p0, p1);
  }
}

// ---------------------------------------------------------------- staging:
// one K-tile (A 256x32 + B 256x32 bf16) -> LDS buffer, 4 gload_lds16/thread.
// Linear LDS dest + pre-swizzled global source chunk: c = c' ^ ((row>>1)&3).
DEV void stage_tile(const unsigned short* __restrict__ Ag, int lda,
                    const unsigned short* __restrict__ Bg, int ldb,
                    int kt, unsigned short* buf, int tid) {
  #pragma unroll
  for (int i = 0; i < 2; i++) {
    const int idx = i * 512 + tid;
    const int row = idx >> 2, cp = idx & 3;
    const int c = cp ^ ((row >> 1) & 3);
    gload_lds16(Ag + (size_t)row * lda + kt + c * 8, buf + idx * 8);
  }
  #pragma unroll
  for (int i = 0; i < 2; i++) {
    const int idx = i * 512 + tid;
    const int row = idx >> 2, cp = idx & 3;
    const int c = cp ^ ((row >> 1) & 3);
    gload_lds16(Bg + (size_t)row * ldb + kt + c * 8, buf + BUF_HALF + idx * 8);
  }
}

// ---------------------------------------------------------------- GEMM core:
// 256x256 tile, BK=32, 8 waves (2M x 4N), 3-buffer LDS distance-2 pipeline,
// counted vmcnt(4) (never drains in steady state), raw s_barrier, setprio.
DEV void gemm256(const unsigned short* __restrict__ Ag, int lda,
                 const unsigned short* __restrict__ Bg, int ldb,
                 int K, unsigned short* lds, f32x4 acc[8][4]) {
  const int tid = threadIdx.x;
  const int l = tid & 63, w = tid >> 6;
  const int wr = w >> 2, wc = w & 3;
  const int lr = l & 15, lk = l >> 4;

  #pragma unroll
  for (int mi = 0; mi < 8; mi++)
    #pragma unroll
    for (int ni = 0; ni < 4; ni++)
      #pragma unroll
      for (int q = 0; q < 4; q++) acc[mi][ni][q] = 0.f;

  const int NT = K / 32;
  unsigned short* bc  = lds;
  unsigned short* bn1 = lds + BUF_SZ;
  unsigned short* bn2 = lds + 2 * BUF_SZ;

  stage_tile(Ag, lda, Bg, ldb, 0, bc, tid);
  stage_tile(Ag, lda, Bg, ldb, 32, bn1, tid);
  __builtin_amdgcn_sched_barrier(0);
  asm volatile("s_waitcnt vmcnt(4)" ::: "memory");   // tile0 complete, tile1 in flight
  __builtin_amdgcn_sched_barrier(0);
  __builtin_amdgcn_s_barrier();
  __builtin_amdgcn_sched_barrier(0);

  for (int t = 0; t < NT; t++) {
    bf16x8 af[8], bv[4];
    #pragma unroll
    for (int mi = 0; mi < 8; mi++) {
      const int row = wr * 128 + mi * 16 + lr;
      const int c = lk ^ ((row >> 1) & 3);
      af[mi] = *(const bf16x8*)(bc + row * 32 + c * 8);
    }
    #pragma unroll
    for (int ni = 0; ni < 4; ni++) {
      const int row = wc * 64 + ni * 16 + lr;
      const int c = lk ^ ((row >> 1) & 3);
      bv[ni] = *(const bf16x8*)(bc + BUF_HALF + row * 32 + c * 8);
    }
    if (t + 2 < NT) stage_tile(Ag, lda, Bg, ldb, (t + 2) * 32, bn2, tid);

    __builtin_amdgcn_s_setprio(1);
    #pragma unroll
    for (int mi = 0; mi < 8; mi++)
      #pragma unroll
      for (int ni = 0; ni < 4; ni++)
        acc[mi][ni] = __builtin_amdgcn_mfma_f32_16x16x32_bf16(af[mi], bv[ni], acc[mi][ni], 0, 0, 0);
    __builtin_amdgcn_s_setprio(0);
    __builtin_amdgcn_sched_barrier(0);
    if (t + 2 < NT) {
      asm volatile("s_waitcnt vmcnt(4)" ::: "memory");  // tile t+1 done; t+2 in flight
    } else {
      asm volatile("s_waitcnt vmcnt(0)" ::: "memory");  // tail drain (last 2 iters)
    }
    __builtin_amdgcn_sched_barrier(0);
    __builtin_amdgcn_s_barrier();
    __builtin_amdgcn_sched_barrier(0);
    unsigned short* tmp = bc; bc = bn1; bn1 = bn2; bn2 = tmp;
  }
}

// ---------------------------------------------------------------- QKV:
// q/k row-major bf16; v written transposed vT[b][d][s] via 2-half LDS transpose.
__global__ __launch_bounds__(512, 2) void qkv_kernel(
    const unsigned short* __restrict__ xbf, const unsigned short* __restrict__ Wt,
    const float* __restrict__ bq, const float* __restrict__ bk,
    const float* __restrict__ bv,
    unsigned short* __restrict__ qo, unsigned short* __restrict__ ko,
    unsigned short* __restrict__ vT) {
  __shared__ unsigned short lds[3 * BUF_SZ];
  const int orig = blockIdx.x;                    // 768 blocks
  const int wg = (orig & 7) * 96 + (orig >> 3);   // bijective XCD swizzle
  const int which = wg >> 8;
  const int rem = wg & 255;
  const int m0 = (rem >> 2) * 256, n0 = (rem & 3) * 256;
  const unsigned short* Ag = xbf + (size_t)m0 * Dn;
  const unsigned short* Bg = Wt + (size_t)which * Dn * Dn + (size_t)n0 * Dn;
  f32x4 acc[8][4];
  gemm256(Ag, Dn, Bg, Dn, Dn, lds, acc);

  const float* bias = which == 0 ? bq : (which == 1 ? bk : bv);
  const int tid = threadIdx.x;
  const int l = tid & 63, w = tid >> 6;
  const int wr = w >> 2, wc = w & 3;
  const int lr = l & 15, lk = l >> 4;

  if (which < 2) {
    unsigned short* out = which == 0 ? qo : ko;
    #pragma unroll
    for (int mi = 0; mi < 8; mi++) {
      #pragma unroll
      for (int ni = 0; ni < 4; ni++) {
        const int col = n0 + wc * 64 + ni * 16 + lr;
        const float bcol = bias[col];
        #pragma unroll
        for (int j = 0; j < 4; j++) {
          const int row = m0 + wr * 128 + mi * 16 + lk * 4 + j;
          out[(size_t)row * Dn + col] = f2bf(fmaxf(acc[mi][ni][j] + bcol, 0.f));
        }
      }
    }
  } else {
    // two 128-s halves through a [256 d][128 s] swizzled LDS transpose buffer
    const int b = m0 >> 11;
    const int s0g = m0 & (Sn - 1);
    #pragma unroll 1
    for (int h = 0; h < 2; h++) {
      if (wr == h) {
        #pragma unroll
        for (int mi = 0; mi < 8; mi++) {
          const int sc = mi * 4 + lk;       // 8B chunk of 4 s-values
          #pragma unroll
          for (int ni = 0; ni < 4; ni++) {
            const int d = wc * 64 + ni * 16 + lr;
            const float bcol = bias[n0 + d];
            unsigned short o0 = f2bf(fmaxf(acc[mi][ni][0] + bcol, 0.f));
            unsigned short o1 = f2bf(fmaxf(acc[mi][ni][1] + bcol, 0.f));
            unsigned short o2 = f2bf(fmaxf(acc[mi][ni][2] + bcol, 0.f));
            unsigned short o3 = f2bf(fmaxf(acc[mi][ni][3] + bcol, 0.f));
            const int scp = sc ^ (d & 31);
            *(uint2*)&lds[d * 128 + scp * 4] =
                make_uint2((unsigned int)o0 | ((unsigned int)o1 << 16),
                           (unsigned int)o2 | ((unsigned int)o3 << 16));
          }
        }
      }
      __syncthreads();
      #pragma unroll
      for (int it = 0; it < 16; it++) {
        const int lin = it * 512 + tid;
        const int d = lin >> 5, sc = lin & 31;
        const int scp = sc ^ (d & 31);
        uint2 v = *(const uint2*)&lds[d * 128 + scp * 4];
        *(uint2*)&vT[((size_t)b * Dn + n0 + d) * Sn + s0g + h * 128 + sc * 4] = v;
      }
      __syncthreads();
    }
  }
}

// ---------------------------------------------------------------- scores:
// P[b][q][k] = mask_k==0 ? 0 : exp(q.k/32)  (unnormalized bf16);
// lpart[b][q][nx] = partial row sums.
__global__ __launch_bounds__(512, 2) void scores_kernel(
    const unsigned short* __restrict__ qbf, const unsigned short* __restrict__ kbf,
    const float* __restrict__ masks, unsigned short* __restrict__ P,
    float* __restrict__ lpart) {
  __shared__ unsigned short lds[3 * BUF_SZ];
  const int orig = blockIdx.x;                    // 512 blocks
  const int wg = (orig & 7) * 64 + (orig >> 3);
  const int b = wg >> 6;
  const int rem = wg & 63;
  const int m0 = (rem >> 3) * 256, n0 = (rem & 7) * 256;
  const unsigned short* Ag = qbf + ((size_t)b * Sn + m0) * Dn;
  const unsigned short* Bg = kbf + ((size_t)b * Sn + n0) * Dn;
  f32x4 acc[8][4];
  gemm256(Ag, Dn, Bg, Dn, Dn, lds, acc);

  const int tid = threadIdx.x;
  const int l = tid & 63, w = tid >> 6;
  const int wr = w >> 2, wc = w & 3;
  const int lr = l & 15, lk = l >> 4;

  float rs[8][4];
  #pragma unroll
  for (int mi = 0; mi < 8; mi++)
    #pragma unroll
    for (int j = 0; j < 4; j++) rs[mi][j] = 0.f;

  unsigned short* Pb = P + (size_t)b * Sn * Sn;
  #pragma unroll
  for (int ni = 0; ni < 4; ni++) {
    const int col = n0 + wc * 64 + ni * 16 + lr;
    const float mk = masks[b * Sn + col];
    const bool dead = (mk == 0.f);
    #pragma unroll
    for (int mi = 0; mi < 8; mi++) {
      #pragma unroll
      for (int j = 0; j < 4; j++) {
        const float s = acc[mi][ni][j] * 0.03125f;   // 1/sqrt(1024)
        const float p = dead ? 0.f : __expf(s);      // s>=0: no overflow
        const unsigned short pq = f2bf(p);
        const int row = m0 + wr * 128 + mi * 16 + lk * 4 + j;
        Pb[(size_t)row * Sn + col] = pq;
        rs[mi][j] += bf2f(pq);                       // sum what PV reads
      }
    }
  }
  #pragma unroll
  for (int mi = 0; mi < 8; mi++)
    #pragma unroll
    for (int j = 0; j < 4; j++) {
      float v = rs[mi][j];
      v += __shfl_xor(v, 1); v += __shfl_xor(v, 2);
      v += __shfl_xor(v, 4); v += __shfl_xor(v, 8);
      rs[mi][j] = v;
    }
  float* psum = (float*)lds;    // 4 x 256 floats, staging is dead now
  if (lr == 0) {
    #pragma unroll
    for (int mi = 0; mi < 8; mi++)
      #pragma unroll
      for (int j = 0; j < 4; j++)
        psum[wc * 256 + wr * 128 + mi * 16 + lk * 4 + j] = rs[mi][j];
  }
  __syncthreads();
  if (tid < 256) {
    const float v = psum[tid] + psum[256 + tid] + psum[512 + tid] + psum[768 + tid];
    lpart[((size_t)b * Sn + m0 + tid) * 8 + (rem & 7)] = v;
  }
}

// ---------------------------------------------------------------- reduce:
// scale[b][q] = mask_q / sum_k P
__global__ __launch_bounds__(256) void reduce_kernel(const float* __restrict__ lpart,
                                                     const float* __restrict__ masks,
                                                     float* __restrict__ scale) {
  const int r = blockIdx.x * 256 + threadIdx.x;
  const float4* p = (const float4*)(lpart + (size_t)r * 8);
  float4 a = p[0], b = p[1];
  const float sum = ((a.x + a.y) + (a.z + a.w)) + ((b.x + b.y) + (b.z + b.w));
  scale[r] = masks[r] / sum;
}

// ---------------------------------------------------------------- PV:
// out[b][q][d] = (P[b] @ vT[b]^T)*scale + q_residual
__global__ __launch_bounds__(512, 2) void pv_kernel(
    const unsigned short* __restrict__ P, const unsigned short* __restrict__ vT,
    const float* __restrict__ scale, const unsigned short* __restrict__ qbf,
    float* __restrict__ out) {
  __shared__ unsigned short lds[3 * BUF_SZ];
  const int orig = blockIdx.x;                    // 256 blocks
  const int wg = (orig & 7) * 32 + (orig >> 3);
  const int b = wg >> 5;
  const int rem = wg & 31;
  const int m0 = (rem >> 2) * 256, n0 = (rem & 3) * 256;
  const unsigned short* Ag = P + (size_t)b * Sn * Sn + (size_t)m0 * Sn;
  const unsigned short* Bg = vT + (size_t)b * Dn * Sn + (size_t)n0 * Sn;
  f32x4 acc[8][4];
  gemm256(Ag, Sn, Bg, Sn, Sn, lds, acc);

  const int tid = threadIdx.x;
  const int l = tid & 63, w = tid >> 6;
  const int wr = w >> 2, wc = w & 3;
  const int lr = l & 15, lk = l >> 4;
  #pragma unroll
  for (int mi = 0; mi < 8; mi++) {
    #pragma unroll
    for (int j = 0; j < 4; j++) {
      const int row = m0 + wr * 128 + mi * 16 + lk * 4 + j;
      const float sc = scale[b * Sn + row];
      const size_t rbase = ((size_t)b * Sn + row) * Dn;
      #pragma unroll
      for (int ni = 0; ni < 4; ni++) {
        const int col = n0 + wc * 64 + ni * 16 + lr;
        out[rbase + col] = acc[mi][ni][j] * sc + bf2f(qbf[rbase + col]);
      }
    }
  }
}

// ---------------------------------------------------------------- launch
extern "C" void kernel_launch(void* const* d_in, const int* in_sizes, int n_in,
                              void* d_out, int out_size, void* d_ws, size_t ws_size,
                              hipStream_t stream) {
  const float* x  = (const float*)d_in[0];
  const float* Wq = (const float*)d_in[1];
  const float* bq = (const float*)d_in[2];
  const float* Wk = (const float*)d_in[3];
  const float* bk = (const float*)d_in[4];
  const float* Wv = (const float*)d_in[5];
  const float* bv = (const float*)d_in[6];
  float* out = (float*)d_out;

  char* ws = (char*)d_ws;
  size_t off = 0;
  auto alloc = [&](size_t bytes) {
    char* p = ws + off;
    off += (bytes + 255) & ~(size_t)255;
    return p;
  };
  unsigned short* xbf = (unsigned short*)alloc((size_t)Mtot * Dn * 2);
  unsigned short* qbf = (unsigned short*)alloc((size_t)Mtot * Dn * 2);
  unsigned short* kbf = (unsigned short*)alloc((size_t)Mtot * Dn * 2);
  unsigned short* vT  = (unsigned short*)alloc((size_t)Bn * Dn * Sn * 2);
  unsigned short* P   = (unsigned short*)alloc((size_t)Bn * Sn * Sn * 2);
  unsigned short* Wt  = (unsigned short*)alloc((size_t)3 * Dn * Dn * 2);
  float* masks = (float*)alloc((size_t)Mtot * 4);
  float* lpart = (float*)alloc((size_t)Mtot * 8 * 4);
  float* scale = (float*)alloc((size_t)Mtot * 4);

  prep_kernel<<<Mtot / 4, 256, 0, stream>>>(x, xbf, masks);
  wt_kernel<<<dim3(32, 32, 3), 256, 0, stream>>>(Wq, Wk, Wv, Wt);
  qkv_kernel<<<768, 512, 0, stream>>>(xbf, Wt, bq, bk, bv, qbf, kbf, vT);
  scores_kernel<<<512, 512, 0, stream>>>(qbf, kbf, masks, P, lpart);
  reduce_kernel<<<Mtot / 256, 256, 0, stream>>>(lpart, masks, scale);
  pv_kernel<<<256, 512, 0, stream>>>(P, vT, scale, qbf, out);
}

// Round 3
// 277.481 us; speedup vs baseline: 1.3166x; 1.2958x over previous
//
#include <hip/hip_runtime.h>

#define DEV __device__ __forceinline__

typedef __attribute__((ext_vector_type(8))) short bf16x8;
typedef __attribute__((ext_vector_type(4))) float f32x4;

static constexpr int Bn = 8;
static constexpr int Sn = 2048;
static constexpr int Dn = 1024;
static constexpr int Mtot = Bn * Sn;   // 16384

// 4 ring buffers; each: A[256][32] + B[256][32] bf16 = 16384 shorts (32KB).
static constexpr int BUFS = 16384;
static constexpr int BHALF = 8192;

DEV void gload_lds16(const void* g, void* l) {
  __builtin_amdgcn_global_load_lds(
      (const __attribute__((address_space(1))) void*)g,
      (__attribute__((address_space(3))) void*)l, 16, 0, 0);
}

DEV float bf2f(unsigned short u) {
  union { unsigned int i; float f; } c;
  c.i = ((unsigned int)u) << 16;
  return c.f;
}
DEV unsigned short f2bf(float f) {
  union { float f; unsigned int i; } c;
  c.f = f;
  unsigned int lsb = (c.i >> 16) & 1u;
  return (unsigned short)((c.i + 0x7fffu + lsb) >> 16);
}

// ---------------------------------------------------------------- prep
__global__ __launch_bounds__(256) void prep_kernel(const float* __restrict__ x,
                                                   unsigned short* __restrict__ xbf,
                                                   float* __restrict__ masks) {
  const int w = threadIdx.x >> 6, l = threadIdx.x & 63;
  const int row = blockIdx.x * 4 + w;
  const float* xr = x + (size_t)row * Dn;
  unsigned short* xo = xbf + (size_t)row * Dn;
  float s = 0.f;
  #pragma unroll
  for (int i = 0; i < 4; i++) {
    float4 v = ((const float4*)xr)[i * 64 + l];
    s += (v.x + v.y) + (v.z + v.w);
    unsigned int p0 = (unsigned int)f2bf(v.x) | ((unsigned int)f2bf(v.y) << 16);
    unsigned int p1 = (unsigned int)f2bf(v.z) | ((unsigned int)f2bf(v.w) << 16);
    *(uint2*)&xo[i * 256 + l * 4] = make_uint2(p0, p1);
  }
  #pragma unroll
  for (int off = 32; off > 0; off >>= 1) s += __shfl_xor(s, off);
  if (l == 0) masks[row] = sinf(fabsf(s));
}

// ---------------------------------------------------------------- Wt
__global__ __launch_bounds__(256) void wt_kernel(const float* __restrict__ Wq,
                                                 const float* __restrict__ Wk,
                                                 const float* __restrict__ Wv,
                                                 unsigned short* __restrict__ Wt) {
  const float* W = blockIdx.z == 0 ? Wq : (blockIdx.z == 1 ? Wk : Wv);
  unsigned short* out = Wt + (size_t)blockIdx.z * Dn * Dn;
  __shared__ float tile[32][33];
  const int r0 = blockIdx.y * 32, c0 = blockIdx.x * 32;
  const int t = threadIdx.x;
  {
    const int r = t >> 3, c4 = (t & 7) * 4;
    float4 v = *(const float4*)&W[(size_t)(r0 + r) * Dn + c0 + c4];
    tile[r][c4 + 0] = v.x; tile[r][c4 + 1] = v.y;
    tile[r][c4 + 2] = v.z; tile[r][c4 + 3] = v.w;
  }
  __syncthreads();
  {
    const int f = t >> 3, d4 = (t & 7) * 4;
    unsigned short o[4];
    #pragma unroll
    for (int i = 0; i < 4; i++) o[i] = f2bf(tile[d4 + i][f]);
    unsigned int p0 = (unsigned int)o[0] | ((unsigned int)o[1] << 16);
    unsigned int p1 = (unsigned int)o[2] | ((unsigned int)o[3] << 16);
    *(uint2*)&out[(size_t)(c0 + f) * Dn + r0 + d4] = make_uint2(p0, p1);
  }
}

// ---------------------------------------------------------------- GEMM core:
// 256x256 tile, BK=32, 8 waves (2Mx4N), 4-buffer LDS ring, stage distance 3,
// vmcnt(8) steady-state (never drains until the tail), one barrier per tile,
// 2x16-MFMA phases with setprio. LDS as 128B lines, chunk ^= (line&7) swizzle
// applied on the pre-swizzled global SOURCE (linear LDS dest), and on reads.
DEV void gemm256(const unsigned short* __restrict__ Ag, int lda,
                 const unsigned short* __restrict__ Bg, int ldb,
                 int K, unsigned short* lds, f32x4 acc[8][4]) {
  const int tid = threadIdx.x;
  const int l = tid & 63, w = tid >> 6;
  const int wr = w >> 2, wc = w & 3;
  const int lr = l & 15, lk = l >> 4;

  #pragma unroll
  for (int mi = 0; mi < 8; mi++)
    #pragma unroll
    for (int ni = 0; ni < 4; ni++)
      #pragma unroll
      for (int q = 0; q < 4; q++) acc[mi][ni][q] = 0.f;

  // loop-invariant LDS read offsets (shorts). Logical (row, kchunk=lk):
  // line L=row>>1, logical chunk e=(row&1)*4+lk, physical p=e^(L&7).
  int offA[8], offB[4];
  #pragma unroll
  for (int mi = 0; mi < 8; mi++) {
    const int row = wr * 128 + mi * 16 + lr;
    const int L = row >> 1, p = ((row & 1) * 4 + lk) ^ (L & 7);
    offA[mi] = L * 64 + p * 8;
  }
  #pragma unroll
  for (int ni = 0; ni < 4; ni++) {
    const int row = wc * 64 + ni * 16 + lr;
    const int L = row >> 1, p = ((row & 1) * 4 + lk) ^ (L & 7);
    offB[ni] = L * 64 + p * 8;
  }
  // loop-invariant stage offsets: dest chunk ci -> (L,p); source logical
  // e = p^(L&7) -> row=2L+(e>>2), kchunk=e&3.
  int sA[2], sB[2], dO[2];
  #pragma unroll
  for (int i = 0; i < 2; i++) {
    const int ci = i * 512 + tid;
    const int L = ci >> 3, p = ci & 7, e = p ^ (L & 7);
    const int grow = 2 * L + (e >> 2), gkc = e & 3;
    sA[i] = grow * lda + gkc * 8;
    sB[i] = grow * ldb + gkc * 8;
    dO[i] = ci * 8;
  }

  const int NT = K >> 5;
  // prologue: stage tiles 0,1,2 (12 loads/thread); wait tile0 (8 remain).
  #pragma unroll
  for (int t = 0; t < 3; t++) {
    unsigned short* bf = lds + t * BUFS;
    gload_lds16(Ag + sA[0] + t * 32, bf + dO[0]);
    gload_lds16(Ag + sA[1] + t * 32, bf + dO[1]);
    gload_lds16(Bg + sB[0] + t * 32, bf + BHALF + dO[0]);
    gload_lds16(Bg + sB[1] + t * 32, bf + BHALF + dO[1]);
  }
  asm volatile("s_waitcnt vmcnt(8)\n\ts_barrier" ::: "memory");

  for (int t = 0; t < NT; t++) {
    unsigned short* bufc = lds + (t & 3) * BUFS;
    unsigned short* bufs = lds + ((t + 3) & 3) * BUFS;
    const bool st = (t + 3 < NT);
    const int kt = (t + 3) * 32;

    bf16x8 af[8], bv[4];
    #pragma unroll
    for (int mi = 0; mi < 8; mi++) af[mi] = *(const bf16x8*)(bufc + offA[mi]);
    bv[0] = *(const bf16x8*)(bufc + BHALF + offB[0]);
    bv[1] = *(const bf16x8*)(bufc + BHALF + offB[1]);
    if (st) {
      gload_lds16(Ag + sA[0] + kt, bufs + dO[0]);
      gload_lds16(Ag + sA[1] + kt, bufs + dO[1]);
    }
    __builtin_amdgcn_s_setprio(1);
    #pragma unroll
    for (int mi = 0; mi < 8; mi++) {
      acc[mi][0] = __builtin_amdgcn_mfma_f32_16x16x32_bf16(af[mi], bv[0], acc[mi][0], 0, 0, 0);
      acc[mi][1] = __builtin_amdgcn_mfma_f32_16x16x32_bf16(af[mi], bv[1], acc[mi][1], 0, 0, 0);
    }
    __builtin_amdgcn_s_setprio(0);
    bv[2] = *(const bf16x8*)(bufc + BHALF + offB[2]);
    bv[3] = *(const bf16x8*)(bufc + BHALF + offB[3]);
    if (st) {
      gload_lds16(Bg + sB[0] + kt, bufs + BHALF + dO[0]);
      gload_lds16(Bg + sB[1] + kt, bufs + BHALF + dO[1]);
    }
    __builtin_amdgcn_s_setprio(1);
    #pragma unroll
    for (int mi = 0; mi < 8; mi++) {
      acc[mi][2] = __builtin_amdgcn_mfma_f32_16x16x32_bf16(af[mi], bv[2], acc[mi][2], 0, 0, 0);
      acc[mi][3] = __builtin_amdgcn_mfma_f32_16x16x32_bf16(af[mi], bv[3], acc[mi][3], 0, 0, 0);
    }
    __builtin_amdgcn_s_setprio(0);

    if (t < NT - 3) {
      asm volatile("s_waitcnt vmcnt(8)\n\ts_barrier" ::: "memory");
    } else if (t == NT - 3) {
      asm volatile("s_waitcnt vmcnt(4)\n\ts_barrier" ::: "memory");
    } else if (t == NT - 2) {
      asm volatile("s_waitcnt vmcnt(0)\n\ts_barrier" ::: "memory");
    }
    // t == NT-1: no wait/barrier; epilogues sync before LDS reuse.
  }
}

// ---------------------------------------------------------------- QKV
__global__ __launch_bounds__(512, 2) void qkv_kernel(
    const unsigned short* __restrict__ xbf, const unsigned short* __restrict__ Wt,
    const float* __restrict__ bq, const float* __restrict__ bk,
    const float* __restrict__ bv,
    unsigned short* __restrict__ qo, unsigned short* __restrict__ ko,
    unsigned short* __restrict__ vT) {
  __shared__ __align__(16) unsigned short lds[4 * BUFS];
  const int orig = blockIdx.x;                    // 768 blocks
  const int wg = (orig & 7) * 96 + (orig >> 3);   // bijective XCD swizzle
  const int which = wg >> 8;
  const int rem = wg & 255;
  const int m0 = (rem >> 2) * 256, n0 = (rem & 3) * 256;
  const unsigned short* Ag = xbf + (size_t)m0 * Dn;
  const unsigned short* Bg = Wt + (size_t)which * Dn * Dn + (size_t)n0 * Dn;
  f32x4 acc[8][4];
  gemm256(Ag, Dn, Bg, Dn, Dn, lds, acc);

  const float* bias = which == 0 ? bq : (which == 1 ? bk : bv);
  const int tid = threadIdx.x;
  const int l = tid & 63, w = tid >> 6;
  const int wr = w >> 2, wc = w & 3;
  const int lr = l & 15, lk = l >> 4;

  if (which < 2) {
    unsigned short* out = which == 0 ? qo : ko;
    #pragma unroll
    for (int mi = 0; mi < 8; mi++) {
      #pragma unroll
      for (int ni = 0; ni < 4; ni++) {
        const int col = n0 + wc * 64 + ni * 16 + lr;
        const float bcol = bias[col];
        #pragma unroll
        for (int j = 0; j < 4; j++) {
          const int row = m0 + wr * 128 + mi * 16 + lk * 4 + j;
          out[(size_t)row * Dn + col] = f2bf(fmaxf(acc[mi][ni][j] + bcol, 0.f));
        }
      }
    }
  } else {
    // two 128-s halves through a [256 d][128 s] swizzled LDS transpose buffer
    const int b = m0 >> 11;
    const int s0g = m0 & (Sn - 1);
    #pragma unroll 1
    for (int h = 0; h < 2; h++) {
      __syncthreads();   // h=0: staging LDS now dead; h=1: prev reads done
      if (wr == h) {
        #pragma unroll
        for (int mi = 0; mi < 8; mi++) {
          const int sc = mi * 4 + lk;       // 8B chunk of 4 s-values
          #pragma unroll
          for (int ni = 0; ni < 4; ni++) {
            const int d = wc * 64 + ni * 16 + lr;
            const float bcol = bias[n0 + d];
            unsigned short o0 = f2bf(fmaxf(acc[mi][ni][0] + bcol, 0.f));
            unsigned short o1 = f2bf(fmaxf(acc[mi][ni][1] + bcol, 0.f));
            unsigned short o2 = f2bf(fmaxf(acc[mi][ni][2] + bcol, 0.f));
            unsigned short o3 = f2bf(fmaxf(acc[mi][ni][3] + bcol, 0.f));
            const int scp = sc ^ (d & 31);
            *(uint2*)&lds[d * 128 + scp * 4] =
                make_uint2((unsigned int)o0 | ((unsigned int)o1 << 16),
                           (unsigned int)o2 | ((unsigned int)o3 << 16));
          }
        }
      }
      __syncthreads();
      #pragma unroll
      for (int it = 0; it < 16; it++) {
        const int lin = it * 512 + tid;
        const int d = lin >> 5, sc = lin & 31;
        const int scp = sc ^ (d & 31);
        uint2 v = *(const uint2*)&lds[d * 128 + scp * 4];
        *(uint2*)&vT[((size_t)b * Dn + n0 + d) * Sn + s0g + h * 128 + sc * 4] = v;
      }
    }
  }
}

// ---------------------------------------------------------------- scores:
// P[b][q][k] = mask_k==0 ? 0 : exp(q.k/32) (unnormalized bf16);
// lpart[b][q][nx] = partial row sums. Low-pressure epilogue: per-(mi,j).
__global__ __launch_bounds__(512, 2) void scores_kernel(
    const unsigned short* __restrict__ qbf, const unsigned short* __restrict__ kbf,
    const float* __restrict__ masks, unsigned short* __restrict__ P,
    float* __restrict__ lpart) {
  __shared__ __align__(16) unsigned short lds[4 * BUFS];
  const int orig = blockIdx.x;                    // 512 blocks
  const int wg = (orig & 7) * 64 + (orig >> 3);
  const int b = wg >> 6;
  const int rem = wg & 63;
  const int m0 = (rem >> 3) * 256, n0 = (rem & 7) * 256;
  const unsigned short* Ag = qbf + ((size_t)b * Sn + m0) * Dn;
  const unsigned short* Bg = kbf + ((size_t)b * Sn + n0) * Dn;
  f32x4 acc[8][4];
  gemm256(Ag, Dn, Bg, Dn, Dn, lds, acc);

  const int tid = threadIdx.x;
  const int l = tid & 63, w = tid >> 6;
  const int wr = w >> 2, wc = w & 3;
  const int lr = l & 15, lk = l >> 4;

  __syncthreads();               // staging LDS dead; reuse for psum
  float* psum = (float*)lds;     // [4 wc][256 rows]

  float mkv[4];
  #pragma unroll
  for (int ni = 0; ni < 4; ni++) mkv[ni] = masks[b * Sn + n0 + wc * 64 + ni * 16 + lr];

  unsigned short* Pb = P + (size_t)b * Sn * Sn;
  #pragma unroll
  for (int mi = 0; mi < 8; mi++) {
    #pragma unroll
    for (int j = 0; j < 4; j++) {
      const int rloc = wr * 128 + mi * 16 + lk * 4 + j;
      const size_t rbase = (size_t)(m0 + rloc) * Sn;
      float rsum = 0.f;
      #pragma unroll
      for (int ni = 0; ni < 4; ni++) {
        const int col = n0 + wc * 64 + ni * 16 + lr;
        const float p = (mkv[ni] == 0.f) ? 0.f : __expf(acc[mi][ni][j] * 0.03125f);
        const unsigned short pq = f2bf(p);
        Pb[rbase + col] = pq;
        rsum += bf2f(pq);
      }
      rsum += __shfl_xor(rsum, 1); rsum += __shfl_xor(rsum, 2);
      rsum += __shfl_xor(rsum, 4); rsum += __shfl_xor(rsum, 8);
      if (lr == 0) psum[wc * 256 + rloc] = rsum;
    }
  }
  __syncthreads();
  if (tid < 256) {
    const float v = psum[tid] + psum[256 + tid] + psum[512 + tid] + psum[768 + tid];
    lpart[((size_t)b * Sn + m0 + tid) * 8 + (rem & 7)] = v;
  }
}

// ---------------------------------------------------------------- reduce
__global__ __launch_bounds__(256) void reduce_kernel(const float* __restrict__ lpart,
                                                     const float* __restrict__ masks,
                                                     float* __restrict__ scale) {
  const int r = blockIdx.x * 256 + threadIdx.x;
  const float4* p = (const float4*)(lpart + (size_t)r * 8);
  float4 a = p[0], b = p[1];
  const float sum = ((a.x + a.y) + (a.z + a.w)) + ((b.x + b.y) + (b.z + b.w));
  scale[r] = masks[r] / sum;
}

// ---------------------------------------------------------------- PV
__global__ __launch_bounds__(512, 2) void pv_kernel(
    const unsigned short* __restrict__ P, const unsigned short* __restrict__ vT,
    const float* __restrict__ scale, const unsigned short* __restrict__ qbf,
    float* __restrict__ out) {
  __shared__ __align__(16) unsigned short lds[4 * BUFS];
  const int orig = blockIdx.x;                    // 256 blocks
  const int wg = (orig & 7) * 32 + (orig >> 3);
  const int b = wg >> 5;
  const int rem = wg & 31;
  const int m0 = (rem >> 2) * 256, n0 = (rem & 3) * 256;
  const unsigned short* Ag = P + (size_t)b * Sn * Sn + (size_t)m0 * Sn;
  const unsigned short* Bg = vT + (size_t)b * Dn * Sn + (size_t)n0 * Sn;
  f32x4 acc[8][4];
  gemm256(Ag, Sn, Bg, Sn, Sn, lds, acc);

  const int tid = threadIdx.x;
  const int l = tid & 63, w = tid >> 6;
  const int wr = w >> 2, wc = w & 3;
  const int lr = l & 15, lk = l >> 4;
  #pragma unroll
  for (int mi = 0; mi < 8; mi++) {
    #pragma unroll
    for (int j = 0; j < 4; j++) {
      const int row = m0 + wr * 128 + mi * 16 + lk * 4 + j;
      const float sc = scale[b * Sn + row];
      const size_t rbase = ((size_t)b * Sn + row) * Dn;
      #pragma unroll
      for (int ni = 0; ni < 4; ni++) {
        const int col = n0 + wc * 64 + ni * 16 + lr;
        out[rbase + col] = acc[mi][ni][j] * sc + bf2f(qbf[rbase + col]);
      }
    }
  }
}

// ---------------------------------------------------------------- launch
extern "C" void kernel_launch(void* const* d_in, const int* in_sizes, int n_in,
                              void* d_out, int out_size, void* d_ws, size_t ws_size,
                              hipStream_t stream) {
  const float* x  = (const float*)d_in[0];
  const float* Wq = (const float*)d_in[1];
  const float* bq = (const float*)d_in[2];
  const float* Wk = (const float*)d_in[3];
  const float* bk = (const float*)d_in[4];
  const float* Wv = (const float*)d_in[5];
  const float* bv = (const float*)d_in[6];
  float* out = (float*)d_out;

  char* ws = (char*)d_ws;
  size_t off = 0;
  auto alloc = [&](size_t bytes) {
    char* p = ws + off;
    off += (bytes + 255) & ~(size_t)255;
    return p;
  };
  unsigned short* xbf = (unsigned short*)alloc((size_t)Mtot * Dn * 2);
  unsigned short* qbf = (unsigned short*)alloc((size_t)Mtot * Dn * 2);
  unsigned short* kbf = (unsigned short*)alloc((size_t)Mtot * Dn * 2);
  unsigned short* vT  = (unsigned short*)alloc((size_t)Bn * Dn * Sn * 2);
  unsigned short* P   = (unsigned short*)alloc((size_t)Bn * Sn * Sn * 2);
  unsigned short* Wt  = (unsigned short*)alloc((size_t)3 * Dn * Dn * 2);
  float* masks = (float*)alloc((size_t)Mtot * 4);
  float* lpart = (float*)alloc((size_t)Mtot * 8 * 4);
  float* scale = (float*)alloc((size_t)Mtot * 4);

  prep_kernel<<<Mtot / 4, 256, 0, stream>>>(x, xbf, masks);
  wt_kernel<<<dim3(32, 32, 3), 256, 0, stream>>>(Wq, Wk, Wv, Wt);
  qkv_kernel<<<768, 512, 0, stream>>>(xbf, Wt, bq, bk, bv, qbf, kbf, vT);
  scores_kernel<<<512, 512, 0, stream>>>(qbf, kbf, masks, P, lpart);
  reduce_kernel<<<Mtot / 256, 256, 0, stream>>>(lpart, masks, scale);
  pv_kernel<<<256, 512, 0, stream>>>(P, vT, scale, qbf, out);
}